// Round 30
// baseline (552.110 us; speedup 1.0000x reference)
//
#include <hip/hip_runtime.h>
#include <hip/hip_bf16.h>
#include <math.h>

#define B_   2
#define S_   4096
#define D_   768
#define H_   12
#define DH_  64
#define BS_  16
#define NB_  256
#define FF_  3072
#define BT_  (B_ * S_)          // 8192 token rows
#define SCALE_F 0.125f          // 1/sqrt(64)

#define NSPLIT 32               // key-dimension splits for edge attention
#define TILES_PER_SPLIT (NB_ / NSPLIT)   // 8
#define NEDGE (B_ * H_ * 2)     // 48 edge (b,h,e) groups
#define NSPARSE (B_ * H_ * NB_) // 6144 sparse work items
#define NXCD 8

// head-major qkv layout: [which][b][h][s][64]; which-stride in f16:
#define QKVSTRIDE ((size_t)BT_ * 768)
#define HSSZ ((size_t)S_ * 64)

typedef _Float16 f16x8 __attribute__((ext_vector_type(8)));
typedef _Float16 f16x4 __attribute__((ext_vector_type(4)));
typedef _Float16 f16x2 __attribute__((ext_vector_type(2)));
typedef float    f32x4 __attribute__((ext_vector_type(4)));
typedef float    f32x16 __attribute__((ext_vector_type(16)));

#define DKS 8                   // disc pool k-splits
#define DKC (D_ / DKS)          // 96 rows per split

// legacy K=16 f16 MFMA: spelled WITHOUT underscore before f16 (r24)
#define MFMA_PV(a, b, c) __builtin_amdgcn_mfma_f32_16x16x16f16(a, b, c, 0, 0, 0)

// XCD-aware swizzle (T1): valid bijection when nwg % NXCD == 0.
__device__ __forceinline__ int xcd_swz(int bid, int nwg)
{
    int q = nwg / NXCD;
    return (bid % NXCD) * q + bid / NXCD;
}

// async global->LDS, 16B per lane; LDS dest is wave-uniform base + lane*16
#define GLD16(gp, lp) __builtin_amdgcn_global_load_lds( \
    (const __attribute__((address_space(1))) void*)(gp), \
    (__attribute__((address_space(3))) void*)(lp), 16, 0, 0)

__device__ __forceinline__ float fast_tanh(float z)
{
    float az = fabsf(z);
    float t = __expf(-2.0f * az);
    float r = (1.0f - t) / (1.0f + t);
    return z < 0.f ? -r : r;
}

__device__ __forceinline__ float gelu_tanh(float v)
{
    float v3 = v * v * v;
    return 0.5f * v * (1.0f + fast_tanh(0.79788456080286535588f * (v + 0.044715f * v3)));
}

// ---------------------------------------------------------------------------
// Fused weight convert + embedding (vectorized transpose).
// ---------------------------------------------------------------------------
struct WSeg { const float* src; _Float16* dst; int K; int N; int start; };
struct WSegs { WSeg s[8]; int total; };

__global__ __launch_bounds__(256) void prep_all(
    WSegs segs, const int* __restrict__ ids, const float* __restrict__ emb,
    _Float16* __restrict__ xh)
{
    int bt = blockIdx.x;
    int t = threadIdx.x;
    if (bt < segs.total) {
        __shared__ float tile[32][33];
        int si = 0;
#pragma unroll
        for (int u = 1; u < 8; ++u)
            if (bt >= segs.s[u].start) si = u;
        const WSeg& sg = segs.s[si];
        int tid = bt - sg.start;
        int tn = sg.N >> 5;
        int n0 = (tid % tn) * 32;
        int k0 = (tid / tn) * 32;

        {
            int r = t >> 3, c = (t & 7) * 4;
            f32x4 v = *(const f32x4*)&sg.src[(size_t)(k0 + r) * sg.N + n0 + c];
            tile[r][c + 0] = v[0];
            tile[r][c + 1] = v[1];
            tile[r][c + 2] = v[2];
            tile[r][c + 3] = v[3];
        }
        __syncthreads();
        {
            int r = t >> 3, c = (t & 7) * 4;
            f16x4 o;
            o[0] = (_Float16)tile[c + 0][r];
            o[1] = (_Float16)tile[c + 1][r];
            o[2] = (_Float16)tile[c + 2][r];
            o[3] = (_Float16)tile[c + 3][r];
            *(f16x4*)&sg.dst[(size_t)(n0 + r) * sg.K + k0 + c] = o;
        }
    } else {
        int row = bt - segs.total;
        int id = ids[row];
        const float* src = emb + (size_t)id * D_;
        _Float16* dst16 = xh + (size_t)row * D_;
        for (int d = t; d < D_; d += 256)
            dst16[d] = (_Float16)src[d];
    }
}

// ---------------------------------------------------------------------------
// MFMA fp16 GEMM (r22, verified). OUTM: 0 = f32 row-major, 1 = f16
// row-major, 2 = f16 head-major qkv permute [which][b][h][s][64] (r29 —
// makes attention's K/Q/V tile reads contiguous 2KB blocks instead of
// 16-way row-strided gathers).
// ---------------------------------------------------------------------------
template<int MI, int DBUF, int ACT, int OUTM>
__global__ __launch_bounds__(256) void gemm_f16(
    const _Float16* __restrict__ A, const _Float16* __restrict__ Wt,
    const float* __restrict__ bias, void* __restrict__ Cp,
    int M, int N, int K, int NT128)
{
    constexpr int BM = MI * 64;
    constexpr int QA = 2 * MI;          // A 1KB chunks per wave
    constexpr int ASZ = BM * 64;        // f16 elems per A buffer
    constexpr int BSZ = 128 * 64;       // f16 elems per B buffer

    __shared__ __attribute__((aligned(16))) _Float16 As[(DBUF ? 2 : 1) * ASZ];
    __shared__ __attribute__((aligned(16))) _Float16 Bs[(DBUF ? 2 : 1) * BSZ];

    int t = threadIdx.x;
    int w = t >> 6, l = t & 63;
    int swz = xcd_swz(blockIdx.x, gridDim.x);
    int bm = (swz / NT128) * BM, bn = (swz % NT128) * 128;
    int wr = (w >> 1) * (MI * 32), wc = (w & 1) * 64;

    f32x16 acc[MI][2];
#pragma unroll
    for (int i = 0; i < MI; ++i)
#pragma unroll
        for (int j = 0; j < 2; ++j)
#pragma unroll
            for (int r = 0; r < 16; ++r) acc[i][j][r] = 0.f;

    const _Float16* gA[QA];
    const _Float16* gB[4];
#pragma unroll
    for (int q = 0; q < QA; ++q) {
        int m = w * QA + q;
        int row = m * 8 + (l >> 3);
        int sc = (l & 7) ^ (row & 7);
        gA[q] = A + (size_t)(bm + row) * K + sc * 8;
    }
#pragma unroll
    for (int q = 0; q < 4; ++q) {
        int m = w * 4 + q;
        int row = m * 8 + (l >> 3);
        int sc = (l & 7) ^ (row & 7);
        gB[q] = Wt + (size_t)(bn + row) * K + sc * 8;
    }

    int aoff[4][MI], boff[4][2];
#pragma unroll
    for (int kk = 0; kk < 4; ++kk) {
        int ch = (kk * 2 + (l >> 5)) ^ (l & 7);
#pragma unroll
        for (int i = 0; i < MI; ++i)
            aoff[kk][i] = (wr + i * 32 + (l & 31)) * 64 + ch * 8;
#pragma unroll
        for (int j = 0; j < 2; ++j)
            boff[kk][j] = (wc + j * 32 + (l & 31)) * 64 + ch * 8;
    }

#define STAGE_(BUF, K0)                                                   \
    {                                                                     \
        _Float16* ab_ = As + (BUF) * ASZ;                                 \
        _Float16* bb_ = Bs + (BUF) * BSZ;                                 \
        _Pragma("unroll")                                                 \
        for (int q = 0; q < QA; ++q)                                      \
            GLD16(gA[q] + (K0), ab_ + (w * QA + q) * 512);                \
        _Pragma("unroll")                                                 \
        for (int q = 0; q < 4; ++q)                                       \
            GLD16(gB[q] + (K0), bb_ + (w * 4 + q) * 512);                 \
    }

#define COMPUTE_(BUF)                                                     \
    {                                                                     \
        const _Float16* ab_ = As + (BUF) * ASZ;                           \
        const _Float16* bb_ = Bs + (BUF) * BSZ;                           \
        _Pragma("unroll")                                                 \
        for (int kk = 0; kk < 4; ++kk) {                                  \
            f16x8 af[MI], bf[2];                                          \
            _Pragma("unroll")                                             \
            for (int i = 0; i < MI; ++i)                                  \
                af[i] = *(const f16x8*)(ab_ + aoff[kk][i]);               \
            _Pragma("unroll")                                             \
            for (int j = 0; j < 2; ++j)                                   \
                bf[j] = *(const f16x8*)(bb_ + boff[kk][j]);               \
            _Pragma("unroll")                                             \
            for (int i = 0; i < MI; ++i)                                  \
                _Pragma("unroll")                                         \
                for (int j = 0; j < 2; ++j)                               \
                    acc[i][j] = __builtin_amdgcn_mfma_f32_32x32x16_f16(   \
                        af[i], bf[j], acc[i][j], 0, 0, 0);                \
        }                                                                 \
    }

    if (DBUF) {
        STAGE_(0, 0);
        __syncthreads();
        int cur = 0;
#pragma unroll 2
        for (int k0 = 0; k0 < K; k0 += 64) {
            if (k0 + 64 < K) STAGE_(cur ^ 1, k0 + 64);
            COMPUTE_(cur);
            __syncthreads();
            cur ^= 1;
        }
    } else {
        for (int k0 = 0; k0 < K; k0 += 64) {
            STAGE_(0, k0);
            __syncthreads();
            COMPUTE_(0);
            __syncthreads();
        }
    }
#undef STAGE_
#undef COMPUTE_

#pragma unroll
    for (int i = 0; i < MI; ++i) {
#pragma unroll
        for (int j = 0; j < 2; ++j) {
            int col = bn + wc + j * 32 + (l & 31);
            float bv = bias[col];
            int which = 0, hh = 0, dd = 0;
            if (OUTM == 2) {
                which = (col >= 1536) ? 2 : ((col >= 768) ? 1 : 0);
                int rem = col - which * 768;
                hh = rem >> 6;
                dd = rem & 63;
            }
#pragma unroll
            for (int rg = 0; rg < 4; ++rg) {
                int row0 = bm + wr + i * 32 + 8 * rg + 4 * (l >> 5);
#pragma unroll
                for (int r = 0; r < 4; ++r) {
                    float v = acc[i][j][rg * 4 + r] + bv;
                    if (ACT) v = gelu_tanh(v);
                    if (OUTM == 2) {
                        int row = row0 + r;
                        int bb = row >> 12, srow = row & 4095;
                        ((_Float16*)Cp)[(size_t)(which * B_ * H_ + bb * H_ + hh) * HSSZ
                                        + (size_t)srow * 64 + dd] = (_Float16)v;
                    } else if (OUTM == 1) {
                        ((_Float16*)Cp)[(size_t)(row0 + r) * N + col] = (_Float16)v;
                    } else {
                        ((float*)Cp)[(size_t)(row0 + r) * N + col] = v;
                    }
                }
            }
        }
    }
}

// ---------------------------------------------------------------------------
// MFMA attention (r23/r24 structure, r29 head-major layout: K/Q/V tiles are
// contiguous 2KB blocks -> fully coalesced wave loads, no row-gathers).
// ---------------------------------------------------------------------------
template<int NT, bool EDGE>
__device__ __forceinline__ void attn_wave(
    const _Float16* __restrict__ qkvp, const int* __restrict__ key_idx,
    _Float16* __restrict__ outp, float* __restrict__ pm,
    float* __restrict__ pl, float* __restrict__ pacc,
    int b, int h, int n, int split, int be,
    _Float16 (*vq)[24])
{
    int l = threadIdx.x & 63;
    int q = l & 15;          // query (score B / P-A row); also key for staging
    int g = l >> 4;          // k-group

    const _Float16* qh = qkvp + (size_t)(b * H_ + h) * HSSZ;
    const _Float16* kh = qh + QKVSTRIDE;
    const _Float16* vh = kh + QKVSTRIDE;

    // Q fragments (B-operand): Q[query=q][k = g*8+u (+32 for half 1)]
    const _Float16* qp = qh + (size_t)(n * BS_ + q) * 64 + g * 8;
    f16x8 qf0 = *(const f16x8*)qp;
    f16x8 qf1 = *(const f16x8*)(qp + 32);

    float m_old = -1e30f, lsum = 0.f;
    f32x4 o[4];
#pragma unroll
    for (int db = 0; db < 4; ++db) o[db] = (f32x4){0.f, 0.f, 0.f, 0.f};

#pragma unroll 1
    for (int jj = 0; jj < NT; ++jj) {
        int kb = EDGE ? (split * NT + jj) : key_idx[n * 7 + jj];
        size_t tro = (size_t)(kb * BS_ + q) * 64;

        // K fragments (A-operand): K[key=q][k = g*8+u (+32)]
        f16x8 kf0 = *(const f16x8*)(kh + tro + g * 8);
        f16x8 kf1 = *(const f16x8*)(kh + tro + g * 8 + 32);

        // stage V: lane covers key=q, d-range g*16..+16 -> vq[d][key]
        {
            const _Float16* vp = vh + tro + g * 16;
            f16x8 v0 = *(const f16x8*)vp;
            f16x8 v1 = *(const f16x8*)(vp + 8);
#pragma unroll
            for (int u = 0; u < 8; ++u) vq[g * 16 + u][q] = v0[u];
#pragma unroll
            for (int u = 0; u < 8; ++u) vq[g * 16 + 8 + u][q] = v1[u];
        }

        // scores: D[key][query] = K x Q over k=0..63
        f32x4 sc = (f32x4){0.f, 0.f, 0.f, 0.f};
        sc = __builtin_amdgcn_mfma_f32_16x16x32_f16(kf0, qf0, sc, 0, 0, 0);
        sc = __builtin_amdgcn_mfma_f32_16x16x32_f16(kf1, qf1, sc, 0, 0, 0);
#pragma unroll
        for (int r = 0; r < 4; ++r) sc[r] *= SCALE_F;

        // online softmax per query (lanes q, q+16, q+32, q+48 share a query)
        float tm = fmaxf(fmaxf(sc[0], sc[1]), fmaxf(sc[2], sc[3]));
        tm = fmaxf(tm, __shfl_xor(tm, 16, 64));
        tm = fmaxf(tm, __shfl_xor(tm, 32, 64));
        float m_new = fmaxf(m_old, tm);

        float pr[4];
        float rs = 0.f;
#pragma unroll
        for (int r = 0; r < 4; ++r) { pr[r] = __expf(sc[r] - m_new); rs += pr[r]; }
        rs += __shfl_xor(rs, 16, 64);
        rs += __shfl_xor(rs, 32, 64);

        float corr = __expf(m_old - m_new);
        lsum = lsum * corr + rs;
        m_old = m_new;

        // rescale O (rows q' = g*4+r): fetch corr per row via shfl
        float cq[4];
#pragma unroll
        for (int r = 0; r < 4; ++r) cq[r] = __shfl(corr, g * 4 + r, 64);
#pragma unroll
        for (int db = 0; db < 4; ++db)
#pragma unroll
            for (int r = 0; r < 4; ++r) o[db][r] *= cq[r];

        // P -> f16 A-fragment (layout already correct: pa[u] = P[q][g*4+u])
        f16x4 pa;
#pragma unroll
        for (int r = 0; r < 4; ++r) pa[r] = (_Float16)pr[r];

        // PV: for each 16-wide d-block, B-frag = V[k=g*4+u][d=db*16+q]
#pragma unroll
        for (int db = 0; db < 4; ++db) {
            f16x4 vb = *(const f16x4*)&vq[db * 16 + q][g * 4];
            o[db] = MFMA_PV(pa, vb, o[db]);
        }
    }

    if (EDGE) {
        int base16 = (be * NSPLIT + split) * 16;
        if (l < 16) { pm[base16 + l] = m_old; pl[base16 + l] = lsum; }
#pragma unroll
        for (int db = 0; db < 4; ++db)
#pragma unroll
            for (int r = 0; r < 4; ++r)
                pacc[(size_t)(base16 + g * 4 + r) * 64 + db * 16 + q] = o[db][r];
    } else {
        float linv[4];
#pragma unroll
        for (int r = 0; r < 4; ++r) linv[r] = 1.f / __shfl(lsum, g * 4 + r, 64);
#pragma unroll
        for (int r = 0; r < 4; ++r) {
            _Float16* dst = outp + ((size_t)(b * S_ + n * BS_ + g * 4 + r)) * D_ + h * DH_ + q;
#pragma unroll
            for (int db = 0; db < 4; ++db)
                dst[db * 16] = (_Float16)(o[db][r] * linv[r]);
        }
    }
}

// ---------------------------------------------------------------------------
// Fused attention dispatch: 4 independent waves per block (no barriers).
// ---------------------------------------------------------------------------
__global__ __launch_bounds__(256) void attn_fused(
    const _Float16* __restrict__ qkvp, const int* __restrict__ key_idx,
    _Float16* __restrict__ outp, float* __restrict__ pm,
    float* __restrict__ pl, float* __restrict__ pacc)
{
    __shared__ __attribute__((aligned(16))) _Float16 vqs[4][64][24];

    int w = threadIdx.x >> 6;
    int bi = xcd_swz(blockIdx.x, gridDim.x) * 4 + w;

    if (bi < NSPARSE) {
        int n = bi % NB_;
        if (n == 0 || n == NB_ - 1) return;   // per-wave exit; kernel has no barriers
        int h = (bi / NB_) % H_;
        int b = bi / (NB_ * H_);
        attn_wave<7, false>(qkvp, key_idx, outp, nullptr, nullptr, nullptr,
                            b, h, n, 0, 0, vqs[w]);
    } else {
        int ei = bi - NSPARSE;
        int split = ei % NSPLIT;
        int be = ei / NSPLIT;
        int e = be & 1;
        int h = (be >> 1) % H_;
        int b = be / (2 * H_);
        int n = e ? (NB_ - 1) : 0;
        attn_wave<TILES_PER_SPLIT, true>(qkvp, nullptr, nullptr, pm, pl, pacc,
                                         b, h, n, split, be, vqs[w]);
    }
}

// ---------------------------------------------------------------------------
// Edge attention combine (unchanged layout)
// ---------------------------------------------------------------------------
__global__ __launch_bounds__(256) void attn_edge_combine(
    const float* __restrict__ pm, const float* __restrict__ pl,
    const float* __restrict__ pacc, _Float16* __restrict__ outp)
{
    int be = blockIdx.x;
    int e = be & 1;
    int h = (be >> 1) % H_;
    int b = be / (2 * H_);
    int n = e ? (NB_ - 1) : 0;

    int t = threadIdx.x;
    int i = t >> 4;
    int c = t & 15;

    float M = -1e30f;
#pragma unroll 4
    for (int s = 0; s < NSPLIT; ++s)
        M = fmaxf(M, pm[(be * NSPLIT + s) * 16 + i]);

    float L = 0.f;
    float acc[4] = {0.f, 0.f, 0.f, 0.f};
    for (int s = 0; s < NSPLIT; ++s) {
        int ps = (be * NSPLIT + s) * 16 + i;
        float wgt = __expf(pm[ps] - M);
        L += pl[ps] * wgt;
#pragma unroll
        for (int u = 0; u < 4; ++u) acc[u] += pacc[(size_t)ps * 64 + c * 4 + u] * wgt;
    }

    float inv = 1.f / L;
    _Float16* dst = outp + ((size_t)(b * S_ + n * BS_ + i)) * D_ + h * DH_ + c * 4;
#pragma unroll
    for (int u = 0; u < 4; ++u) dst[u] = (_Float16)(acc[u] * inv);
}

// ---------------------------------------------------------------------------
// LN: residual stream in f16. xh = LN(xh + g) (stats in f32).
// ---------------------------------------------------------------------------
template<int WRITE32>
__global__ __launch_bounds__(256) void add_ln_kernel(
    _Float16* __restrict__ xh, const _Float16* __restrict__ g,
    const float* __restrict__ gamma, const float* __restrict__ beta,
    float* __restrict__ x32)
{
    int row = blockIdx.x;
    int t = threadIdx.x;
    _Float16* xr = xh + (size_t)row * D_;
    const _Float16* gr = g + (size_t)row * D_;

    float v[3];
    float s = 0.f, s2 = 0.f;
#pragma unroll
    for (int r = 0; r < 3; ++r) {
        int d = t + 256 * r;
        v[r] = (float)xr[d] + (float)gr[d];
        s += v[r];
        s2 += v[r] * v[r];
    }
#pragma unroll
    for (int off = 32; off; off >>= 1) {
        s  += __shfl_xor(s, off, 64);
        s2 += __shfl_xor(s2, off, 64);
    }
    __shared__ float sA[4], sB[4];
    int wave = t >> 6, lane = t & 63;
    if (lane == 0) { sA[wave] = s; sB[wave] = s2; }
    __syncthreads();
    s  = sA[0] + sA[1] + sA[2] + sA[3];
    s2 = sB[0] + sB[1] + sB[2] + sB[3];
    float mean = s * (1.0f / D_);
    float var = s2 * (1.0f / D_) - mean * mean;
    float rstd = rsqrtf(var + 1e-12f);
#pragma unroll
    for (int r = 0; r < 3; ++r) {
        int d = t + 256 * r;
        float o = (v[r] - mean) * rstd * gamma[d] + beta[d];
        xr[d] = (_Float16)o;
        if (WRITE32) x32[(size_t)row * D_ + d] = o;
    }
}

// ---------------------------------------------------------------------------
// Fused heads: blockIdx < 2048 -> start/end logits; else disc pool partial.
// ---------------------------------------------------------------------------
__global__ __launch_bounds__(256) void heads_fused(
    const float* __restrict__ x, const float* __restrict__ sw,
    const float* __restrict__ ew, const float* __restrict__ Wp,
    float* __restrict__ sl, float* __restrict__ el,
    float* __restrict__ partial)
{
    int bi = blockIdx.x;
    int t = threadIdx.x;
    if (bi < 2048) {
        int wave = t >> 6, lane = t & 63;
        int row = bi * 4 + wave;
        const float* xr = x + (size_t)row * D_;
        float a = 0.f, e = 0.f;
        for (int d = lane; d < D_; d += 64) {
            float xv = xr[d];
            a += xv * sw[d];
            e += xv * ew[d];
        }
#pragma unroll
        for (int off = 32; off; off >>= 1) {
            a += __shfl_xor(a, off, 64);
            e += __shfl_xor(e, off, 64);
        }
        if (lane == 0) { sl[row] = a; el[row] = e; }
    } else {
        int ei = bi - 2048;       // 0..23
        int jb = ei % 3;          // 0..2
        int ks = ei / 3;          // 0..7
        int j = jb * 256 + t;
        int k0 = ks * DKC;

        __shared__ float xs[DKC];
        if (t < DKC) xs[t] = x[k0 + t];   // x0 = x row 0
        __syncthreads();

        float s = 0.f;
#pragma unroll 8
        for (int kk = 0; kk < DKC; ++kk)
            s += xs[kk] * Wp[(size_t)(k0 + kk) * D_ + j];
        partial[ks * D_ + j] = s;
    }
}

// ---------------------------------------------------------------------------
// Fused final: r<4 -> softmax over S; r==4 -> disc finish.
// ---------------------------------------------------------------------------
__global__ __launch_bounds__(256) void final_fused(
    const float* __restrict__ sl, const float* __restrict__ el,
    const float* __restrict__ partial, const float* __restrict__ bp,
    const float* __restrict__ d1W, const float* __restrict__ d1b,
    const float* __restrict__ d2W, const float* __restrict__ d2b,
    float* __restrict__ outp)
{
    int r = blockIdx.x;
    int t = threadIdx.x;
    if (r < 4) {
        const float* src = (r < 2 ? sl : el) + (size_t)(r & 1) * S_;
        float* dst = outp + (r < 2 ? 0 : BT_) + (size_t)(r & 1) * S_;
        int wave = t >> 6, lane = t & 63;
        __shared__ float sm[4], ss[4];

        float m = -1e30f;
        for (int k = t; k < S_; k += 256) m = fmaxf(m, src[k]);
#pragma unroll
        for (int off = 32; off; off >>= 1) m = fmaxf(m, __shfl_xor(m, off, 64));
        if (lane == 0) sm[wave] = m;
        __syncthreads();
        m = fmaxf(fmaxf(sm[0], sm[1]), fmaxf(sm[2], sm[3]));

        float s = 0.f;
        for (int k = t; k < S_; k += 256) s += __expf(src[k] - m);
#pragma unroll
        for (int off = 32; off; off >>= 1) s += __shfl_xor(s, off, 64);
        if (lane == 0) ss[wave] = s;
        __syncthreads();
        s = ss[0] + ss[1] + ss[2] + ss[3];

        float inv = 1.f / s;
        for (int k = t; k < S_; k += 256) dst[k] = __expf(src[k] - m) * inv;
    } else {
        __shared__ float pool[D_];
        __shared__ float h1[20];
        float* out2 = outp + 2 * BT_;
        for (int j = t; j < D_; j += 256) {
            float s = bp[j];
#pragma unroll
            for (int ks = 0; ks < DKS; ++ks) s += partial[ks * D_ + j];
            pool[j] = tanhf(s);
        }
        __syncthreads();
        if (t < 20) {
            float s = d1b[t];
            for (int k = 0; k < D_; ++k) s += pool[k] * d1W[k * 20 + t];
            h1[t] = s;
        }
        __syncthreads();
        if (t == 0) {
            float d0 = d2b[0], d1v = d2b[1];
#pragma unroll
            for (int u = 0; u < 20; ++u) {
                d0  += h1[u] * d2W[u * 2 + 0];
                d1v += h1[u] * d2W[u * 2 + 1];
            }
            float m = fmaxf(d0, d1v);
            float e0 = __expf(d0 - m), e1 = __expf(d1v - m);
            float inv = 1.f / (e0 + e1);
            out2[0] = e0 * inv;
            out2[1] = e1 * inv;
        }
    }
}

// ---------------------------------------------------------------------------
extern "C" void kernel_launch(void* const* d_in, const int* in_sizes, int n_in,
                              void* d_out, int out_size, void* d_ws, size_t ws_size,
                              hipStream_t stream)
{
    const int*   ids   = (const int*)d_in[0];
    const int*   kbi   = (const int*)d_in[1];
    const float* emb   = (const float*)d_in[2];
    const float* Wqkv  = (const float*)d_in[3];
    const float* bqkv  = (const float*)d_in[4];
    const float* Wo    = (const float*)d_in[5];
    const float* bo    = (const float*)d_in[6];
    const float* ln1g  = (const float*)d_in[7];
    const float* ln1b  = (const float*)d_in[8];
    const float* Wff1  = (const float*)d_in[9];
    const float* bff1  = (const float*)d_in[10];
    const float* Wff2  = (const float*)d_in[11];
    const float* bff2  = (const float*)d_in[12];
    const float* ln2g  = (const float*)d_in[13];
    const float* ln2b  = (const float*)d_in[14];
    const float* Wp    = (const float*)d_in[15];
    const float* bp    = (const float*)d_in[16];
    const float* sw    = (const float*)d_in[17];
    const float* ew    = (const float*)d_in[18];
    const float* d1W   = (const float*)d_in[19];
    const float* d1b   = (const float*)d_in[20];
    const float* d2W   = (const float*)d_in[21];
    const float* d2b   = (const float*)d_in[22];
    float* outp = (float*)d_out;

    // workspace carve (float units)
    float* ws   = (float*)d_ws;
    float* x    = ws;                          // BT_*D_ f32 (final LN only)
    float* xbf  = x   + (size_t)BT_ * D_;      // f16 xh (residual stream)
    float* r1f  = xbf + (size_t)BT_ * D_ / 2;  // f16 qkv / f16 h
    float* abf  = r1f + (size_t)BT_ * FF_ / 2; // f16 attn out
    float* r2   = abf + (size_t)BT_ * D_ / 2;  // partials (early) / f16 g (late)
    float* wtf  = r2  + (size_t)BT_ * D_;      // f16 weights
    float* sl   = wtf + 7077888;
    float* el   = sl  + BT_;
    float* dpar = el  + BT_;                   // DKS * D_ disc partials

    _Float16* xh    = (_Float16*)xbf;
    _Float16* qkv16 = (_Float16*)r1f;          // head-major [which][b][h][s][64]
    _Float16* h16   = (_Float16*)r1f;
    _Float16* ab    = (_Float16*)abf;
    float* pm   = r2;
    float* pl   = r2 + NEDGE * NSPLIT * 16;
    float* pacc = pl + NEDGE * NSPLIT * 16;
    _Float16* g16 = (_Float16*)r2;   // aliased; partials dead once proj runs

    _Float16* Wt    = (_Float16*)wtf;
    _Float16* WqkvT = Wt;
    _Float16* WoT   = WqkvT + (size_t)2 * 2304 * 768;
    _Float16* Wff1T = WoT   + (size_t)2 * 768 * 768;
    _Float16* Wff2T = Wff1T + (size_t)2 * 3072 * 768;

    // fused weight convert + embed: one dispatch
    WSegs segs;
    int start = 0;
    for (int l = 0; l < 2; ++l) {
        int base = l * 4;
        segs.s[base + 0] = { Wqkv + (size_t)l * 768 * 2304,
                             WqkvT + (size_t)l * 2304 * 768, 768, 2304, start };
        start += (2304 / 32) * (768 / 32);
        segs.s[base + 1] = { Wo + (size_t)l * 768 * 768,
                             WoT + (size_t)l * 768 * 768, 768, 768, start };
        start += (768 / 32) * (768 / 32);
        segs.s[base + 2] = { Wff1 + (size_t)l * 768 * 3072,
                             Wff1T + (size_t)l * 3072 * 768, 768, 3072, start };
        start += (3072 / 32) * (768 / 32);
        segs.s[base + 3] = { Wff2 + (size_t)l * 3072 * 768,
                             Wff2T + (size_t)l * 768 * 3072, 3072, 768, start };
        start += (768 / 32) * (3072 / 32);
    }
    segs.total = start;   // 13824

    prep_all<<<segs.total + BT_, 256, 0, stream>>>(segs, ids, emb, xh);

    for (int l = 0; l < 2; ++l) {
        // qkv: BM=128 single-buffer, head-major permuted output (OUTM=2)
        gemm_f16<2,0,0,2><<<(BT_/128) * (2304/128), 256, 0, stream>>>(
            xh, WqkvT + (size_t)l * 2304 * 768, bqkv + (size_t)l * 3 * D_,
            qkv16, BT_, 3 * D_, D_, 2304/128);
        // attention: 7680 work items, 4 waves/block -> 1920 blocks (no barriers)
        attn_fused<<<(NSPARSE + NEDGE * NSPLIT) / 4, 256, 0, stream>>>(
            qkv16, kbi, ab, pm, pl, pacc);
        attn_edge_combine<<<NEDGE, 256, 0, stream>>>(pm, pl, pacc, ab);
        // proj: BM=64 + 2-phase dbuf, grid 768
        gemm_f16<1,1,0,1><<<(BT_/64) * (768/128), 256, 0, stream>>>(
            ab, WoT + (size_t)l * 768 * 768, bo + (size_t)l * D_,
            g16, BT_, D_, D_, 768/128);
        add_ln_kernel<0><<<BT_, 256, 0, stream>>>(
            xh, g16, ln1g + (size_t)l * D_, ln1b + (size_t)l * D_, nullptr);
        // ff1: BM=128 single-buffer, grid 1536
        gemm_f16<2,0,1,1><<<(BT_/128) * (3072/128), 256, 0, stream>>>(
            xh, Wff1T + (size_t)l * 3072 * 768, bff1 + (size_t)l * FF_,
            h16, BT_, FF_, D_, 3072/128);
        // ff2: BM=64 + 2-phase dbuf, grid 768
        gemm_f16<1,1,0,1><<<(BT_/64) * (768/128), 256, 0, stream>>>(
            h16, Wff2T + (size_t)l * 768 * 3072, bff2 + (size_t)l * D_,
            g16, BT_, D_, FF_, 768/128);
        if (l == 1)
            add_ln_kernel<1><<<BT_, 256, 0, stream>>>(
                xh, g16, ln2g + (size_t)l * D_, ln2b + (size_t)l * D_, x);
        else
            add_ln_kernel<0><<<BT_, 256, 0, stream>>>(
                xh, g16, ln2g + (size_t)l * D_, ln2b + (size_t)l * D_, nullptr);
    }

    heads_fused<<<2048 + 3 * DKS, 256, 0, stream>>>(x, sw, ew, Wp, sl, el, dpar);
    final_fused<<<5, 256, 0, stream>>>(sl, el, dpar, bp, d1W, d1b, d2W, d2b, outp);
}

// Round 31
// 549.101 us; speedup vs baseline: 1.0055x; 1.0055x over previous
//
#include <hip/hip_runtime.h>
#include <hip/hip_bf16.h>
#include <math.h>

#define B_   2
#define S_   4096
#define D_   768
#define H_   12
#define DH_  64
#define BS_  16
#define NB_  256
#define FF_  3072
#define BT_  (B_ * S_)          // 8192 token rows
#define SCALE_F 0.125f          // 1/sqrt(64)

#define NSPLIT 32               // key-dimension splits for edge attention
#define TILES_PER_SPLIT (NB_ / NSPLIT)   // 8
#define NEDGE (B_ * H_ * 2)     // 48 edge (b,h,e) groups
#define NSPARSE (B_ * H_ * NB_) // 6144 sparse work items
#define NXCD 8

// head-major qkv layout: [which][b][h][s][64]; which-stride in f16:
#define QKVSTRIDE ((size_t)BT_ * 768)
#define HSSZ ((size_t)S_ * 64)

typedef _Float16 f16x8 __attribute__((ext_vector_type(8)));
typedef _Float16 f16x4 __attribute__((ext_vector_type(4)));
typedef _Float16 f16x2 __attribute__((ext_vector_type(2)));
typedef float    f32x4 __attribute__((ext_vector_type(4)));
typedef float    f32x16 __attribute__((ext_vector_type(16)));

#define DKS 8                   // disc pool k-splits
#define DKC (D_ / DKS)          // 96 rows per split

// legacy K=16 f16 MFMA: spelled WITHOUT underscore before f16 (r24)
#define MFMA_PV(a, b, c) __builtin_amdgcn_mfma_f32_16x16x16f16(a, b, c, 0, 0, 0)

// XCD-aware swizzle (T1): valid bijection when nwg % NXCD == 0.
__device__ __forceinline__ int xcd_swz(int bid, int nwg)
{
    int q = nwg / NXCD;
    return (bid % NXCD) * q + bid / NXCD;
}

// async global->LDS, 16B per lane; LDS dest is wave-uniform base + lane*16
#define GLD16(gp, lp) __builtin_amdgcn_global_load_lds( \
    (const __attribute__((address_space(1))) void*)(gp), \
    (__attribute__((address_space(3))) void*)(lp), 16, 0, 0)

__device__ __forceinline__ float fast_tanh(float z)
{
    float az = fabsf(z);
    float t = __expf(-2.0f * az);
    float r = (1.0f - t) / (1.0f + t);
    return z < 0.f ? -r : r;
}

__device__ __forceinline__ float gelu_tanh(float v)
{
    float v3 = v * v * v;
    return 0.5f * v * (1.0f + fast_tanh(0.79788456080286535588f * (v + 0.044715f * v3)));
}

// ---------------------------------------------------------------------------
// Fused weight convert + embedding. r31: embed branch vectorized (f32x4 read,
// f16x4 write, lanes 0-191; G13 — scalar loads were ~2x slower).
// ---------------------------------------------------------------------------
struct WSeg { const float* src; _Float16* dst; int K; int N; int start; };
struct WSegs { WSeg s[8]; int total; };

__global__ __launch_bounds__(256) void prep_all(
    WSegs segs, const int* __restrict__ ids, const float* __restrict__ emb,
    _Float16* __restrict__ xh)
{
    int bt = blockIdx.x;
    int t = threadIdx.x;
    if (bt < segs.total) {
        __shared__ float tile[32][33];
        int si = 0;
#pragma unroll
        for (int u = 1; u < 8; ++u)
            if (bt >= segs.s[u].start) si = u;
        const WSeg& sg = segs.s[si];
        int tid = bt - sg.start;
        int tn = sg.N >> 5;
        int n0 = (tid % tn) * 32;
        int k0 = (tid / tn) * 32;

        {
            int r = t >> 3, c = (t & 7) * 4;
            f32x4 v = *(const f32x4*)&sg.src[(size_t)(k0 + r) * sg.N + n0 + c];
            tile[r][c + 0] = v[0];
            tile[r][c + 1] = v[1];
            tile[r][c + 2] = v[2];
            tile[r][c + 3] = v[3];
        }
        __syncthreads();
        {
            int r = t >> 3, c = (t & 7) * 4;
            f16x4 o;
            o[0] = (_Float16)tile[c + 0][r];
            o[1] = (_Float16)tile[c + 1][r];
            o[2] = (_Float16)tile[c + 2][r];
            o[3] = (_Float16)tile[c + 3][r];
            *(f16x4*)&sg.dst[(size_t)(n0 + r) * sg.K + k0 + c] = o;
        }
    } else {
        int row = bt - segs.total;
        int id = ids[row];
        const float* src = emb + (size_t)id * D_;
        _Float16* dst16 = xh + (size_t)row * D_;
        if (t < 192) {
            f32x4 vv = *(const f32x4*)&src[t * 4];
            f16x4 o;
#pragma unroll
            for (int u = 0; u < 4; ++u) o[u] = (_Float16)vv[u];
            *(f16x4*)&dst16[t * 4] = o;
        }
    }
}

// ---------------------------------------------------------------------------
// MFMA fp16 GEMM (r22, verified). OUTM: 0 = f32 row-major, 1 = f16
// row-major, 2 = f16 head-major qkv permute [which][b][h][s][64].
// ---------------------------------------------------------------------------
template<int MI, int DBUF, int ACT, int OUTM>
__global__ __launch_bounds__(256) void gemm_f16(
    const _Float16* __restrict__ A, const _Float16* __restrict__ Wt,
    const float* __restrict__ bias, void* __restrict__ Cp,
    int M, int N, int K, int NT128)
{
    constexpr int BM = MI * 64;
    constexpr int QA = 2 * MI;          // A 1KB chunks per wave
    constexpr int ASZ = BM * 64;        // f16 elems per A buffer
    constexpr int BSZ = 128 * 64;       // f16 elems per B buffer

    __shared__ __attribute__((aligned(16))) _Float16 As[(DBUF ? 2 : 1) * ASZ];
    __shared__ __attribute__((aligned(16))) _Float16 Bs[(DBUF ? 2 : 1) * BSZ];

    int t = threadIdx.x;
    int w = t >> 6, l = t & 63;
    int swz = xcd_swz(blockIdx.x, gridDim.x);
    int bm = (swz / NT128) * BM, bn = (swz % NT128) * 128;
    int wr = (w >> 1) * (MI * 32), wc = (w & 1) * 64;

    f32x16 acc[MI][2];
#pragma unroll
    for (int i = 0; i < MI; ++i)
#pragma unroll
        for (int j = 0; j < 2; ++j)
#pragma unroll
            for (int r = 0; r < 16; ++r) acc[i][j][r] = 0.f;

    const _Float16* gA[QA];
    const _Float16* gB[4];
#pragma unroll
    for (int q = 0; q < QA; ++q) {
        int m = w * QA + q;
        int row = m * 8 + (l >> 3);
        int sc = (l & 7) ^ (row & 7);
        gA[q] = A + (size_t)(bm + row) * K + sc * 8;
    }
#pragma unroll
    for (int q = 0; q < 4; ++q) {
        int m = w * 4 + q;
        int row = m * 8 + (l >> 3);
        int sc = (l & 7) ^ (row & 7);
        gB[q] = Wt + (size_t)(bn + row) * K + sc * 8;
    }

    int aoff[4][MI], boff[4][2];
#pragma unroll
    for (int kk = 0; kk < 4; ++kk) {
        int ch = (kk * 2 + (l >> 5)) ^ (l & 7);
#pragma unroll
        for (int i = 0; i < MI; ++i)
            aoff[kk][i] = (wr + i * 32 + (l & 31)) * 64 + ch * 8;
#pragma unroll
        for (int j = 0; j < 2; ++j)
            boff[kk][j] = (wc + j * 32 + (l & 31)) * 64 + ch * 8;
    }

#define STAGE_(BUF, K0)                                                   \
    {                                                                     \
        _Float16* ab_ = As + (BUF) * ASZ;                                 \
        _Float16* bb_ = Bs + (BUF) * BSZ;                                 \
        _Pragma("unroll")                                                 \
        for (int q = 0; q < QA; ++q)                                      \
            GLD16(gA[q] + (K0), ab_ + (w * QA + q) * 512);                \
        _Pragma("unroll")                                                 \
        for (int q = 0; q < 4; ++q)                                       \
            GLD16(gB[q] + (K0), bb_ + (w * 4 + q) * 512);                 \
    }

#define COMPUTE_(BUF)                                                     \
    {                                                                     \
        const _Float16* ab_ = As + (BUF) * ASZ;                           \
        const _Float16* bb_ = Bs + (BUF) * BSZ;                           \
        _Pragma("unroll")                                                 \
        for (int kk = 0; kk < 4; ++kk) {                                  \
            f16x8 af[MI], bf[2];                                          \
            _Pragma("unroll")                                             \
            for (int i = 0; i < MI; ++i)                                  \
                af[i] = *(const f16x8*)(ab_ + aoff[kk][i]);               \
            _Pragma("unroll")                                             \
            for (int j = 0; j < 2; ++j)                                   \
                bf[j] = *(const f16x8*)(bb_ + boff[kk][j]);               \
            _Pragma("unroll")                                             \
            for (int i = 0; i < MI; ++i)                                  \
                _Pragma("unroll")                                         \
                for (int j = 0; j < 2; ++j)                               \
                    acc[i][j] = __builtin_amdgcn_mfma_f32_32x32x16_f16(   \
                        af[i], bf[j], acc[i][j], 0, 0, 0);                \
        }                                                                 \
    }

    if (DBUF) {
        STAGE_(0, 0);
        __syncthreads();
        int cur = 0;
#pragma unroll 2
        for (int k0 = 0; k0 < K; k0 += 64) {
            if (k0 + 64 < K) STAGE_(cur ^ 1, k0 + 64);
            COMPUTE_(cur);
            __syncthreads();
            cur ^= 1;
        }
    } else {
        for (int k0 = 0; k0 < K; k0 += 64) {
            STAGE_(0, k0);
            __syncthreads();
            COMPUTE_(0);
            __syncthreads();
        }
    }
#undef STAGE_
#undef COMPUTE_

#pragma unroll
    for (int i = 0; i < MI; ++i) {
#pragma unroll
        for (int j = 0; j < 2; ++j) {
            int col = bn + wc + j * 32 + (l & 31);
            float bv = bias[col];
            int which = 0, hh = 0, dd = 0;
            if (OUTM == 2) {
                which = (col >= 1536) ? 2 : ((col >= 768) ? 1 : 0);
                int rem = col - which * 768;
                hh = rem >> 6;
                dd = rem & 63;
            }
#pragma unroll
            for (int rg = 0; rg < 4; ++rg) {
                int row0 = bm + wr + i * 32 + 8 * rg + 4 * (l >> 5);
#pragma unroll
                for (int r = 0; r < 4; ++r) {
                    float v = acc[i][j][rg * 4 + r] + bv;
                    if (ACT) v = gelu_tanh(v);
                    if (OUTM == 2) {
                        int row = row0 + r;
                        int bb = row >> 12, srow = row & 4095;
                        ((_Float16*)Cp)[(size_t)(which * B_ * H_ + bb * H_ + hh) * HSSZ
                                        + (size_t)srow * 64 + dd] = (_Float16)v;
                    } else if (OUTM == 1) {
                        ((_Float16*)Cp)[(size_t)(row0 + r) * N + col] = (_Float16)v;
                    } else {
                        ((float*)Cp)[(size_t)(row0 + r) * N + col] = v;
                    }
                }
            }
        }
    }
}

// ---------------------------------------------------------------------------
// MFMA attention (r23/r24 structure, r29 head-major layout).
// ---------------------------------------------------------------------------
template<int NT, bool EDGE>
__device__ __forceinline__ void attn_wave(
    const _Float16* __restrict__ qkvp, const int* __restrict__ key_idx,
    _Float16* __restrict__ outp, float* __restrict__ pm,
    float* __restrict__ pl, float* __restrict__ pacc,
    int b, int h, int n, int split, int be,
    _Float16 (*vq)[24])
{
    int l = threadIdx.x & 63;
    int q = l & 15;          // query (score B / P-A row); also key for staging
    int g = l >> 4;          // k-group

    const _Float16* qh = qkvp + (size_t)(b * H_ + h) * HSSZ;
    const _Float16* kh = qh + QKVSTRIDE;
    const _Float16* vh = kh + QKVSTRIDE;

    // Q fragments (B-operand): Q[query=q][k = g*8+u (+32 for half 1)]
    const _Float16* qp = qh + (size_t)(n * BS_ + q) * 64 + g * 8;
    f16x8 qf0 = *(const f16x8*)qp;
    f16x8 qf1 = *(const f16x8*)(qp + 32);

    float m_old = -1e30f, lsum = 0.f;
    f32x4 o[4];
#pragma unroll
    for (int db = 0; db < 4; ++db) o[db] = (f32x4){0.f, 0.f, 0.f, 0.f};

#pragma unroll 1
    for (int jj = 0; jj < NT; ++jj) {
        int kb = EDGE ? (split * NT + jj) : key_idx[n * 7 + jj];
        size_t tro = (size_t)(kb * BS_ + q) * 64;

        // K fragments (A-operand): K[key=q][k = g*8+u (+32)]
        f16x8 kf0 = *(const f16x8*)(kh + tro + g * 8);
        f16x8 kf1 = *(const f16x8*)(kh + tro + g * 8 + 32);

        // stage V: lane covers key=q, d-range g*16..+16 -> vq[d][key]
        {
            const _Float16* vp = vh + tro + g * 16;
            f16x8 v0 = *(const f16x8*)vp;
            f16x8 v1 = *(const f16x8*)(vp + 8);
#pragma unroll
            for (int u = 0; u < 8; ++u) vq[g * 16 + u][q] = v0[u];
#pragma unroll
            for (int u = 0; u < 8; ++u) vq[g * 16 + 8 + u][q] = v1[u];
        }

        // scores: D[key][query] = K x Q over k=0..63
        f32x4 sc = (f32x4){0.f, 0.f, 0.f, 0.f};
        sc = __builtin_amdgcn_mfma_f32_16x16x32_f16(kf0, qf0, sc, 0, 0, 0);
        sc = __builtin_amdgcn_mfma_f32_16x16x32_f16(kf1, qf1, sc, 0, 0, 0);
#pragma unroll
        for (int r = 0; r < 4; ++r) sc[r] *= SCALE_F;

        // online softmax per query (lanes q, q+16, q+32, q+48 share a query)
        float tm = fmaxf(fmaxf(sc[0], sc[1]), fmaxf(sc[2], sc[3]));
        tm = fmaxf(tm, __shfl_xor(tm, 16, 64));
        tm = fmaxf(tm, __shfl_xor(tm, 32, 64));
        float m_new = fmaxf(m_old, tm);

        float pr[4];
        float rs = 0.f;
#pragma unroll
        for (int r = 0; r < 4; ++r) { pr[r] = __expf(sc[r] - m_new); rs += pr[r]; }
        rs += __shfl_xor(rs, 16, 64);
        rs += __shfl_xor(rs, 32, 64);

        float corr = __expf(m_old - m_new);
        lsum = lsum * corr + rs;
        m_old = m_new;

        // rescale O (rows q' = g*4+r): fetch corr per row via shfl
        float cq[4];
#pragma unroll
        for (int r = 0; r < 4; ++r) cq[r] = __shfl(corr, g * 4 + r, 64);
#pragma unroll
        for (int db = 0; db < 4; ++db)
#pragma unroll
            for (int r = 0; r < 4; ++r) o[db][r] *= cq[r];

        // P -> f16 A-fragment (layout already correct: pa[u] = P[q][g*4+u])
        f16x4 pa;
#pragma unroll
        for (int r = 0; r < 4; ++r) pa[r] = (_Float16)pr[r];

        // PV: for each 16-wide d-block, B-frag = V[k=g*4+u][d=db*16+q]
#pragma unroll
        for (int db = 0; db < 4; ++db) {
            f16x4 vb = *(const f16x4*)&vq[db * 16 + q][g * 4];
            o[db] = MFMA_PV(pa, vb, o[db]);
        }
    }

    if (EDGE) {
        int base16 = (be * NSPLIT + split) * 16;
        if (l < 16) { pm[base16 + l] = m_old; pl[base16 + l] = lsum; }
#pragma unroll
        for (int db = 0; db < 4; ++db)
#pragma unroll
            for (int r = 0; r < 4; ++r)
                pacc[(size_t)(base16 + g * 4 + r) * 64 + db * 16 + q] = o[db][r];
    } else {
        float linv[4];
#pragma unroll
        for (int r = 0; r < 4; ++r) linv[r] = 1.f / __shfl(lsum, g * 4 + r, 64);
#pragma unroll
        for (int r = 0; r < 4; ++r) {
            _Float16* dst = outp + ((size_t)(b * S_ + n * BS_ + g * 4 + r)) * D_ + h * DH_ + q;
#pragma unroll
            for (int db = 0; db < 4; ++db)
                dst[db * 16] = (_Float16)(o[db][r] * linv[r]);
        }
    }
}

// ---------------------------------------------------------------------------
// Fused attention dispatch: 4 independent waves per block (no barriers).
// ---------------------------------------------------------------------------
__global__ __launch_bounds__(256) void attn_fused(
    const _Float16* __restrict__ qkvp, const int* __restrict__ key_idx,
    _Float16* __restrict__ outp, float* __restrict__ pm,
    float* __restrict__ pl, float* __restrict__ pacc)
{
    __shared__ __attribute__((aligned(16))) _Float16 vqs[4][64][24];

    int w = threadIdx.x >> 6;
    int bi = xcd_swz(blockIdx.x, gridDim.x) * 4 + w;

    if (bi < NSPARSE) {
        int n = bi % NB_;
        if (n == 0 || n == NB_ - 1) return;   // per-wave exit; kernel has no barriers
        int h = (bi / NB_) % H_;
        int b = bi / (NB_ * H_);
        attn_wave<7, false>(qkvp, key_idx, outp, nullptr, nullptr, nullptr,
                            b, h, n, 0, 0, vqs[w]);
    } else {
        int ei = bi - NSPARSE;
        int split = ei % NSPLIT;
        int be = ei / NSPLIT;
        int e = be & 1;
        int h = (be >> 1) % H_;
        int b = be / (2 * H_);
        int n = e ? (NB_ - 1) : 0;
        attn_wave<TILES_PER_SPLIT, true>(qkvp, nullptr, nullptr, pm, pl, pacc,
                                         b, h, n, split, be, vqs[w]);
    }
}

// ---------------------------------------------------------------------------
// Edge attention combine (unchanged layout)
// ---------------------------------------------------------------------------
__global__ __launch_bounds__(256) void attn_edge_combine(
    const float* __restrict__ pm, const float* __restrict__ pl,
    const float* __restrict__ pacc, _Float16* __restrict__ outp)
{
    int be = blockIdx.x;
    int e = be & 1;
    int h = (be >> 1) % H_;
    int b = be / (2 * H_);
    int n = e ? (NB_ - 1) : 0;

    int t = threadIdx.x;
    int i = t >> 4;
    int c = t & 15;

    float M = -1e30f;
#pragma unroll 4
    for (int s = 0; s < NSPLIT; ++s)
        M = fmaxf(M, pm[(be * NSPLIT + s) * 16 + i]);

    float L = 0.f;
    float acc[4] = {0.f, 0.f, 0.f, 0.f};
    for (int s = 0; s < NSPLIT; ++s) {
        int ps = (be * NSPLIT + s) * 16 + i;
        float wgt = __expf(pm[ps] - M);
        L += pl[ps] * wgt;
#pragma unroll
        for (int u = 0; u < 4; ++u) acc[u] += pacc[(size_t)ps * 64 + c * 4 + u] * wgt;
    }

    float inv = 1.f / L;
    _Float16* dst = outp + ((size_t)(b * S_ + n * BS_ + i)) * D_ + h * DH_ + c * 4;
#pragma unroll
    for (int u = 0; u < 4; ++u) dst[u] = (_Float16)(acc[u] * inv);
}

// ---------------------------------------------------------------------------
// LN (r31): residual stream in f16, 1 row/block (keeps r24 TLP), but lanes
// 0-191 each handle 4 elems via f16x4/f32x4 vector loads (G13). Wave 3
// contributes zeros to the cross-wave reduction.
// ---------------------------------------------------------------------------
template<int WRITE32>
__global__ __launch_bounds__(256) void add_ln_kernel(
    _Float16* __restrict__ xh, const _Float16* __restrict__ g,
    const float* __restrict__ gamma, const float* __restrict__ beta,
    float* __restrict__ x32)
{
    int row = blockIdx.x;
    int t = threadIdx.x;
    _Float16* xr = xh + (size_t)row * D_;
    const _Float16* gr = g + (size_t)row * D_;

    int d = t * 4;
    float v[4] = {0.f, 0.f, 0.f, 0.f};
    float s = 0.f, s2 = 0.f;
    if (t < 192) {
        f16x4 xv = *(const f16x4*)&xr[d];
        f16x4 gv = *(const f16x4*)&gr[d];
#pragma unroll
        for (int u = 0; u < 4; ++u) {
            v[u] = (float)xv[u] + (float)gv[u];
            s += v[u];
            s2 += v[u] * v[u];
        }
    }
#pragma unroll
    for (int off = 32; off; off >>= 1) {
        s  += __shfl_xor(s, off, 64);
        s2 += __shfl_xor(s2, off, 64);
    }
    __shared__ float sA[4], sB[4];
    int wave = t >> 6, lane = t & 63;
    if (lane == 0) { sA[wave] = s; sB[wave] = s2; }
    __syncthreads();
    s  = sA[0] + sA[1] + sA[2] + sA[3];
    s2 = sB[0] + sB[1] + sB[2] + sB[3];
    float mean = s * (1.0f / D_);
    float var = s2 * (1.0f / D_) - mean * mean;
    float rstd = rsqrtf(var + 1e-12f);
    if (t < 192) {
        f32x4 gm = *(const f32x4*)&gamma[d];
        f32x4 bt = *(const f32x4*)&beta[d];
        f16x4 ov;
        float o[4];
#pragma unroll
        for (int u = 0; u < 4; ++u) {
            o[u] = (v[u] - mean) * rstd * gm[u] + bt[u];
            ov[u] = (_Float16)o[u];
        }
        *(f16x4*)&xr[d] = ov;
        if (WRITE32)
            *(f32x4*)&x32[(size_t)row * D_ + d] = (f32x4){o[0], o[1], o[2], o[3]};
    }
}

// ---------------------------------------------------------------------------
// Fused heads: blockIdx < 2048 -> start/end logits; else disc pool partial.
// ---------------------------------------------------------------------------
__global__ __launch_bounds__(256) void heads_fused(
    const float* __restrict__ x, const float* __restrict__ sw,
    const float* __restrict__ ew, const float* __restrict__ Wp,
    float* __restrict__ sl, float* __restrict__ el,
    float* __restrict__ partial)
{
    int bi = blockIdx.x;
    int t = threadIdx.x;
    if (bi < 2048) {
        int wave = t >> 6, lane = t & 63;
        int row = bi * 4 + wave;
        const float* xr = x + (size_t)row * D_;
        float a = 0.f, e = 0.f;
        for (int d = lane; d < D_; d += 64) {
            float xv = xr[d];
            a += xv * sw[d];
            e += xv * ew[d];
        }
#pragma unroll
        for (int off = 32; off; off >>= 1) {
            a += __shfl_xor(a, off, 64);
            e += __shfl_xor(e, off, 64);
        }
        if (lane == 0) { sl[row] = a; el[row] = e; }
    } else {
        int ei = bi - 2048;       // 0..23
        int jb = ei % 3;          // 0..2
        int ks = ei / 3;          // 0..7
        int j = jb * 256 + t;
        int k0 = ks * DKC;

        __shared__ float xs[DKC];
        if (t < DKC) xs[t] = x[k0 + t];   // x0 = x row 0
        __syncthreads();

        float s = 0.f;
#pragma unroll 8
        for (int kk = 0; kk < DKC; ++kk)
            s += xs[kk] * Wp[(size_t)(k0 + kk) * D_ + j];
        partial[ks * D_ + j] = s;
    }
}

// ---------------------------------------------------------------------------
// Fused final: r<4 -> softmax over S; r==4 -> disc finish.
// ---------------------------------------------------------------------------
__global__ __launch_bounds__(256) void final_fused(
    const float* __restrict__ sl, const float* __restrict__ el,
    const float* __restrict__ partial, const float* __restrict__ bp,
    const float* __restrict__ d1W, const float* __restrict__ d1b,
    const float* __restrict__ d2W, const float* __restrict__ d2b,
    float* __restrict__ outp)
{
    int r = blockIdx.x;
    int t = threadIdx.x;
    if (r < 4) {
        const float* src = (r < 2 ? sl : el) + (size_t)(r & 1) * S_;
        float* dst = outp + (r < 2 ? 0 : BT_) + (size_t)(r & 1) * S_;
        int wave = t >> 6, lane = t & 63;
        __shared__ float sm[4], ss[4];

        float m = -1e30f;
        for (int k = t; k < S_; k += 256) m = fmaxf(m, src[k]);
#pragma unroll
        for (int off = 32; off; off >>= 1) m = fmaxf(m, __shfl_xor(m, off, 64));
        if (lane == 0) sm[wave] = m;
        __syncthreads();
        m = fmaxf(fmaxf(sm[0], sm[1]), fmaxf(sm[2], sm[3]));

        float s = 0.f;
        for (int k = t; k < S_; k += 256) s += __expf(src[k] - m);
#pragma unroll
        for (int off = 32; off; off >>= 1) s += __shfl_xor(s, off, 64);
        if (lane == 0) ss[wave] = s;
        __syncthreads();
        s = ss[0] + ss[1] + ss[2] + ss[3];

        float inv = 1.f / s;
        for (int k = t; k < S_; k += 256) dst[k] = __expf(src[k] - m) * inv;
    } else {
        __shared__ float pool[D_];
        __shared__ float h1[20];
        float* out2 = outp + 2 * BT_;
        for (int j = t; j < D_; j += 256) {
            float s = bp[j];
#pragma unroll
            for (int ks = 0; ks < DKS; ++ks) s += partial[ks * D_ + j];
            pool[j] = tanhf(s);
        }
        __syncthreads();
        if (t < 20) {
            float s = d1b[t];
            for (int k = 0; k < D_; ++k) s += pool[k] * d1W[k * 20 + t];
            h1[t] = s;
        }
        __syncthreads();
        if (t == 0) {
            float d0 = d2b[0], d1v = d2b[1];
#pragma unroll
            for (int u = 0; u < 20; ++u) {
                d0  += h1[u] * d2W[u * 2 + 0];
                d1v += h1[u] * d2W[u * 2 + 1];
            }
            float m = fmaxf(d0, d1v);
            float e0 = __expf(d0 - m), e1 = __expf(d1v - m);
            float inv = 1.f / (e0 + e1);
            out2[0] = e0 * inv;
            out2[1] = e1 * inv;
        }
    }
}

// ---------------------------------------------------------------------------
extern "C" void kernel_launch(void* const* d_in, const int* in_sizes, int n_in,
                              void* d_out, int out_size, void* d_ws, size_t ws_size,
                              hipStream_t stream)
{
    const int*   ids   = (const int*)d_in[0];
    const int*   kbi   = (const int*)d_in[1];
    const float* emb   = (const float*)d_in[2];
    const float* Wqkv  = (const float*)d_in[3];
    const float* bqkv  = (const float*)d_in[4];
    const float* Wo    = (const float*)d_in[5];
    const float* bo    = (const float*)d_in[6];
    const float* ln1g  = (const float*)d_in[7];
    const float* ln1b  = (const float*)d_in[8];
    const float* Wff1  = (const float*)d_in[9];
    const float* bff1  = (const float*)d_in[10];
    const float* Wff2  = (const float*)d_in[11];
    const float* bff2  = (const float*)d_in[12];
    const float* ln2g  = (const float*)d_in[13];
    const float* ln2b  = (const float*)d_in[14];
    const float* Wp    = (const float*)d_in[15];
    const float* bp    = (const float*)d_in[16];
    const float* sw    = (const float*)d_in[17];
    const float* ew    = (const float*)d_in[18];
    const float* d1W   = (const float*)d_in[19];
    const float* d1b   = (const float*)d_in[20];
    const float* d2W   = (const float*)d_in[21];
    const float* d2b   = (const float*)d_in[22];
    float* outp = (float*)d_out;

    // workspace carve (float units)
    float* ws   = (float*)d_ws;
    float* x    = ws;                          // BT_*D_ f32 (final LN only)
    float* xbf  = x   + (size_t)BT_ * D_;      // f16 xh (residual stream)
    float* r1f  = xbf + (size_t)BT_ * D_ / 2;  // f16 qkv / f16 h
    float* abf  = r1f + (size_t)BT_ * FF_ / 2; // f16 attn out
    float* r2   = abf + (size_t)BT_ * D_ / 2;  // partials (early) / f16 g (late)
    float* wtf  = r2  + (size_t)BT_ * D_;      // f16 weights
    float* sl   = wtf + 7077888;
    float* el   = sl  + BT_;
    float* dpar = el  + BT_;                   // DKS * D_ disc partials

    _Float16* xh    = (_Float16*)xbf;
    _Float16* qkv16 = (_Float16*)r1f;          // head-major [which][b][h][s][64]
    _Float16* h16   = (_Float16*)r1f;
    _Float16* ab    = (_Float16*)abf;
    float* pm   = r2;
    float* pl   = r2 + NEDGE * NSPLIT * 16;
    float* pacc = pl + NEDGE * NSPLIT * 16;
    _Float16* g16 = (_Float16*)r2;   // aliased; partials dead once proj runs

    _Float16* Wt    = (_Float16*)wtf;
    _Float16* WqkvT = Wt;
    _Float16* WoT   = WqkvT + (size_t)2 * 2304 * 768;
    _Float16* Wff1T = WoT   + (size_t)2 * 768 * 768;
    _Float16* Wff2T = Wff1T + (size_t)2 * 3072 * 768;

    // fused weight convert + embed: one dispatch
    WSegs segs;
    int start = 0;
    for (int l = 0; l < 2; ++l) {
        int base = l * 4;
        segs.s[base + 0] = { Wqkv + (size_t)l * 768 * 2304,
                             WqkvT + (size_t)l * 2304 * 768, 768, 2304, start };
        start += (2304 / 32) * (768 / 32);
        segs.s[base + 1] = { Wo + (size_t)l * 768 * 768,
                             WoT + (size_t)l * 768 * 768, 768, 768, start };
        start += (768 / 32) * (768 / 32);
        segs.s[base + 2] = { Wff1 + (size_t)l * 768 * 3072,
                             Wff1T + (size_t)l * 3072 * 768, 768, 3072, start };
        start += (3072 / 32) * (768 / 32);
        segs.s[base + 3] = { Wff2 + (size_t)l * 3072 * 768,
                             Wff2T + (size_t)l * 768 * 3072, 3072, 768, start };
        start += (768 / 32) * (3072 / 32);
    }
    segs.total = start;   // 13824

    prep_all<<<segs.total + BT_, 256, 0, stream>>>(segs, ids, emb, xh);

    for (int l = 0; l < 2; ++l) {
        // qkv: BM=128 single-buffer, head-major permuted output (OUTM=2)
        gemm_f16<2,0,0,2><<<(BT_/128) * (2304/128), 256, 0, stream>>>(
            xh, WqkvT + (size_t)l * 2304 * 768, bqkv + (size_t)l * 3 * D_,
            qkv16, BT_, 3 * D_, D_, 2304/128);
        // attention: 7680 work items, 4 waves/block -> 1920 blocks (no barriers)
        attn_fused<<<(NSPARSE + NEDGE * NSPLIT) / 4, 256, 0, stream>>>(
            qkv16, kbi, ab, pm, pl, pacc);
        attn_edge_combine<<<NEDGE, 256, 0, stream>>>(pm, pl, pacc, ab);
        // proj: BM=64 + 2-phase dbuf, grid 768
        gemm_f16<1,1,0,1><<<(BT_/64) * (768/128), 256, 0, stream>>>(
            ab, WoT + (size_t)l * 768 * 768, bo + (size_t)l * D_,
            g16, BT_, D_, D_, 768/128);
        add_ln_kernel<0><<<BT_, 256, 0, stream>>>(
            xh, g16, ln1g + (size_t)l * D_, ln1b + (size_t)l * D_, nullptr);
        // ff1: BM=128 single-buffer, grid 1536
        gemm_f16<2,0,1,1><<<(BT_/128) * (3072/128), 256, 0, stream>>>(
            xh, Wff1T + (size_t)l * 3072 * 768, bff1 + (size_t)l * FF_,
            h16, BT_, FF_, D_, 3072/128);
        // ff2: BM=64 + 2-phase dbuf, grid 768
        gemm_f16<1,1,0,1><<<(BT_/64) * (768/128), 256, 0, stream>>>(
            h16, Wff2T + (size_t)l * 768 * 3072, bff2 + (size_t)l * D_,
            g16, BT_, D_, FF_, 768/128);
        if (l == 1)
            add_ln_kernel<1><<<BT_, 256, 0, stream>>>(
                xh, g16, ln2g + (size_t)l * D_, ln2b + (size_t)l * D_, x);
        else
            add_ln_kernel<0><<<BT_, 256, 0, stream>>>(
                xh, g16, ln2g + (size_t)l * D_, ln2b + (size_t)l * D_, nullptr);
    }

    heads_fused<<<2048 + 3 * DKS, 256, 0, stream>>>(x, sw, ew, Wp, sl, el, dpar);
    final_fused<<<5, 256, 0, stream>>>(sl, el, dpar, bp, d1W, d1b, d2W, d2b, outp);
}